// Round 7
// baseline (434.093 us; speedup 1.0000x reference)
//
#include <hip/hip_runtime.h>
#include <hip/hip_cooperative_groups.h>
#include <hip/hip_bf16.h>
#include <stdint.h>

namespace cg = cooperative_groups;

// Problem constants (S=1024, B=2 -> T=2048 tokens)
#define TT 2048
#define DD 512
#define FF 2048
#define EE 8

typedef unsigned short u16;
typedef __attribute__((ext_vector_type(8))) unsigned short ushort8v;
typedef __attribute__((ext_vector_type(8))) short short8;     // bf16x8 frag
typedef __attribute__((ext_vector_type(4))) float float4v;

__device__ __forceinline__ u16 f2bf(float f) {
    unsigned u = __float_as_uint(f);
    u += 0x7FFF + ((u >> 16) & 1);   // round-to-nearest-even
    return (u16)(u >> 16);
}

// async global->LDS, 16B/lane; LDS dest = wave-uniform base + lane*16.
// Global address may be per-lane divergent; only the LDS side must be linear.
__device__ __forceinline__ void gl_lds16(const u16* g, u16* l) {
    __builtin_amdgcn_global_load_lds(
        (const __attribute__((address_space(1))) unsigned int*)g,
        (__attribute__((address_space(3))) unsigned int*)l, 16, 0, 0);
}

// ---------------- workspace layout (bytes) ----------------
#define WS_HB   0ull                                // hbuf bf16 [6144][2048]
#define WS_XG   (WS_HB + 6144ull*2048*2)            // xg bf16 [2048][512]
#define WS_WT1  (WS_XG + 2048ull*512*2)             // W1t bf16 [9][F][D]
#define WS_RTG  (WS_WT1 + 9ull*2048*512*2)          // routing int[16] = offs[8],cnt[8]
#define WS_ME   (WS_RTG + 64)                       // int  [2048][2]
#define WS_MW   (WS_ME + 16384)                     // float[2048][2]
#define WS_RT   (WS_MW + 16384)                     // int  rtok[4096]
#define WS_WROW (WS_RT + 16384)                     // float wrow[4096]
#define WS_MR   (WS_WROW + 16384)                   // int  metaR[4096] token->rows
#define WS_WT2  (WS_MR + 16384)                     // W2t bf16 [9][D][F] (big path)
#define WS_YB   (WS_WT2 + 9ull*2048*512*2)          // ybuf fp32 [2][6144][512] (big)
#define WS_BIG  (WS_YB + 2ull*6144*512*4)           // ~90.3 MB

struct Params {
    const float *x, *Wg, *bg, *W1, *b1, *W2, *b2, *Ws1, *bs1, *Ws2, *bs2;
    float* out;
    u16 *hbuf, *xg, *Wt1, *Wt2;
    float* ybuf;
    int* routing; int* metaE; float* metaW; int* rtok; float* wrow; int* metaR;
    int useYb;
};

// ---------------- conv unit: fp32 [R][C] 64x64 tile -> bf16 [C][R] ----------------
__device__ void conv_unit(int j, const float* __restrict__ srcE,
                          const float* __restrict__ srcS, u16* __restrict__ dst,
                          int R, int C, int shC, u16* Ls) {
    int mid = j >> 8, t2 = j & 255;
    int tr = t2 >> shC, tc = t2 & ((1 << shC) - 1);
    int r0 = tr * 64, c0 = tc * 64;
    const float* src = (mid < 8) ? srcE + (size_t)mid * R * C : srcS;
    u16* dstm = dst + (size_t)mid * R * C;
    int t = threadIdx.x;
#pragma unroll
    for (int i = 0; i < 4; ++i) {
        int rr = (t >> 4) + i * 16;
        int cc = (t & 15) * 4;
        float4v v = *(const float4v*)(src + (size_t)(r0 + rr) * C + c0 + cc);
#pragma unroll
        for (int jx = 0; jx < 4; ++jx) Ls[(cc + jx) * 72 + rr] = f2bf(v[jx]);
    }
    __syncthreads();
#pragma unroll
    for (int jj = 0; jj < 2; ++jj) {
        int slot = t + jj * 256;
        int cc = slot >> 3, r8 = (slot & 7) * 8;
        ushort8v o = *(const ushort8v*)&Ls[cc * 72 + r8];
        *(ushort8v*)(dstm + (size_t)(c0 + cc) * R + r0 + r8) = o;
    }
    __syncthreads();   // WAR guard for next job reusing Ls
}

// ---------------- gate: one wave per token (fp32 logits = np ref) ----------------
__device__ void gate_wave(int t, int lane, const Params& p) {
    const float* xp = p.x + (size_t)t * DD + lane * 8;
    float4v x0 = *(const float4v*)xp;
    float4v x1 = *(const float4v*)(xp + 4);
    float xf[8] = {x0[0], x0[1], x0[2], x0[3], x1[0], x1[1], x1[2], x1[3]};
    float acc[EE] = {0.f, 0.f, 0.f, 0.f, 0.f, 0.f, 0.f, 0.f};
#pragma unroll
    for (int g = 0; g < 8; ++g) {
        const float* wp = p.Wg + (size_t)(lane * 8 + g) * EE;
        float4v w0 = *(const float4v*)wp;
        float4v w1 = *(const float4v*)(wp + 4);
        acc[0] += xf[g] * w0[0]; acc[1] += xf[g] * w0[1];
        acc[2] += xf[g] * w0[2]; acc[3] += xf[g] * w0[3];
        acc[4] += xf[g] * w1[0]; acc[5] += xf[g] * w1[1];
        acc[6] += xf[g] * w1[2]; acc[7] += xf[g] * w1[3];
    }
#pragma unroll
    for (int off = 1; off < 64; off <<= 1) {
#pragma unroll
        for (int e = 0; e < EE; ++e) acc[e] += __shfl_xor(acc[e], off, 64);
    }
    ushort8v xv;
#pragma unroll
    for (int jx = 0; jx < 4; ++jx) xv[jx] = f2bf(x0[jx]);
#pragma unroll
    for (int jx = 0; jx < 4; ++jx) xv[4 + jx] = f2bf(x1[jx]);
    *(ushort8v*)(p.xg + (size_t)t * DD + lane * 8) = xv;
    if (lane == 0) {
#pragma unroll
        for (int e = 0; e < EE; ++e) acc[e] += p.bg[e];
        int e0 = 0; float l0 = acc[0];
#pragma unroll
        for (int e = 1; e < EE; ++e) if (acc[e] > l0) { l0 = acc[e]; e0 = e; }
        int e1 = -1; float l1 = -3.4e38f;
#pragma unroll
        for (int e = 0; e < EE; ++e)
            if (e != e0 && acc[e] > l1) { l1 = acc[e]; e1 = e; }
        float ex = __expf(l1 - l0);
        float w0 = 1.f / (1.f + ex);
        p.metaE[2 * t] = e0; p.metaE[2 * t + 1] = e1;
        p.metaW[2 * t] = w0; p.metaW[2 * t + 1] = 1.f - w0;
    }
}

// ---------------- rank: block 0, 256 threads, ballot-based, 0 atomics ----------------
__device__ void rank_block(const Params& p, char* smem) {
    u16* er      = (u16*)smem;            // 4096 x u16 (e | rk<<4)
    int* segCnt  = (int*)(smem + 8192);   // [64][8]
    int* segBase = (int*)(smem + 10240);  // [64][8]
    int* expTot  = (int*)(smem + 12288);  // [16]
    int tid = threadIdx.x, wv = tid >> 6, lane = tid & 63;
    unsigned long long below = (lane == 0) ? 0ull : ((~0ull) >> (64 - lane));
    for (int s = wv * 16; s < wv * 16 + 16; ++s) {
        int entry = s * 64 + lane;
        int e = p.metaE[entry];
        int rk = 0;
#pragma unroll
        for (int ee = 0; ee < 8; ++ee) {
            unsigned long long m = __ballot(e == ee);
            if (e == ee) rk = __popcll(m & below);
            if (lane == ee) segCnt[s * 8 + ee] = __popcll(m);
        }
        er[entry] = (u16)(e | (rk << 4));
    }
    __syncthreads();
    if (tid < 8) {
        int s = 0;
        for (int g = 0; g < 64; ++g) { segBase[g * 8 + tid] = s; s += segCnt[g * 8 + tid]; }
        expTot[tid] = s;
    }
    __syncthreads();
    if (tid == 0) {
        int s = 0;
        for (int e = 0; e < 8; ++e) { int c = expTot[e]; expTot[8 + e] = s; s += c; }
    }
    __syncthreads();
    if (tid < 8) { p.routing[tid] = expTot[8 + tid]; p.routing[8 + tid] = expTot[tid]; }
    for (int i = 0; i < 16; ++i) {
        int entry = tid + i * 256;
        int v = er[entry];
        int e = v & 15, rk = v >> 4;
        int row = expTot[8 + e] + segBase[(entry >> 6) * 8 + e] + rk;
        p.rtok[row] = entry >> 1;
        p.wrow[row] = p.metaW[entry];
        p.metaR[entry] = row;
    }
    __syncthreads();
}

// ---------------- gemmA job: h = relu(A @ W1 + b1), 128x128, BK=64 ----------------
// jobs: [0,256) shared; [256,2304) routed rt-major.
__device__ void gemmA_job(int j, const Params& p, u16* As, u16* Bs) {
    const int* offs = p.routing; const int* cnt = p.routing + 8;
    int tid = threadIdx.x;
    int rt, ct, Mloc, hRowBase, rowBase; bool routed;
    const u16* Bsrc; const float* bias;
    if (j < 256) {
        rt = j >> 4; ct = j & 15; Mloc = 128; rowBase = rt * 128;
        Bsrc = p.Wt1 + (size_t)8 * FF * DD; bias = p.bs1;
        hRowBase = 4096 + rt * 128; routed = false;
    } else {
        int jr = j - 256; rt = jr >> 7; int rem = jr & 127;
        int e = rem >> 4; ct = rem & 15;
        int M = cnt[e]; if (rt * 128 >= M) return;
        Mloc = M - rt * 128; rowBase = offs[e] + rt * 128;
        Bsrc = p.Wt1 + (size_t)e * FF * DD; bias = p.b1 + e * FF;
        hRowBase = rowBase; routed = true;
    }
    int n0 = ct * 128;
    int lane = tid & 63, w = tid >> 6, ln = lane & 15, quad = lane >> 4;
    int l8 = lane & 7, lh = lane >> 3;
    int gc = (l8 ^ lh) * 8;            // XOR-swizzled k-chunk offset (elems)
    const u16* Ab[4];
#pragma unroll
    for (int i = 0; i < 4; ++i) {
        int r = w * 32 + i * 8 + lh;
        int tok;
        if (routed) {
            int br = rowBase + r; if (br > 4095) br = 4095;   // finite, masked below
            tok = p.rtok[br];
        } else tok = rowBase + r;
        Ab[i] = p.xg + (size_t)tok * DD + gc;
    }
    const u16* Bb = Bsrc + (size_t)(n0 + w * 32 + lh) * DD + gc;
    float4v acc[4][4];
#pragma unroll
    for (int a = 0; a < 4; ++a)
#pragma unroll
        for (int b = 0; b < 4; ++b) acc[a][b] = (float4v){0.f, 0.f, 0.f, 0.f};
    for (int kt = 0; kt < 8; ++kt) {
        int k0 = kt * 64;
#pragma unroll
        for (int i = 0; i < 4; ++i) {
            gl_lds16(Ab[i] + k0, &As[(w * 4 + i) * 512]);
            gl_lds16(Bb + (size_t)(i * 8) * DD + k0, &Bs[(w * 4 + i) * 512]);
        }
        __syncthreads();
#pragma unroll
        for (int s = 0; s < 2; ++s) {
            short8 Af[4], Bf[4];
#pragma unroll
            for (int a = 0; a < 4; ++a) {
                int m = (w & 1) * 64 + a * 16 + ln;
                Af[a] = *(const short8*)&As[m * 64 + (((s * 4 + quad) ^ (ln & 7)) * 8)];
            }
#pragma unroll
            for (int b = 0; b < 4; ++b) {
                int m = (w >> 1) * 64 + b * 16 + ln;
                Bf[b] = *(const short8*)&Bs[m * 64 + (((s * 4 + quad) ^ (ln & 7)) * 8)];
            }
#pragma unroll
            for (int a = 0; a < 4; ++a)
#pragma unroll
                for (int b = 0; b < 4; ++b)
                    acc[a][b] = __builtin_amdgcn_mfma_f32_16x16x32_bf16(Af[a], Bf[b], acc[a][b], 0, 0, 0);
        }
        __syncthreads();
    }
#pragma unroll
    for (int b = 0; b < 4; ++b) {
        int n = n0 + (w >> 1) * 64 + b * 16 + ln;
        float bv = bias[n];
#pragma unroll
        for (int a = 0; a < 4; ++a) {
#pragma unroll
            for (int i = 0; i < 4; ++i) {
                int lr = (w & 1) * 64 + a * 16 + quad * 4 + i;
                if (lr < Mloc) {
                    float v = acc[a][b][i] + bv;
                    v = v > 0.f ? v : 0.f;
                    p.hbuf[(size_t)(hRowBase + lr) * FF + n] = f2bf(v);
                }
            }
        }
    }
}

// ---------------- gemmB job: y = w*(h @ W2 + b2), BK=64, K-split x2 ----------------
// jobs: [0,128) shared (rt4|ct2|ks1); [128,1152) routed (rt*64 + e*8 + ct*2 + ks).
__device__ void gemmB_job(int j, const Params& p, u16* As, u16* Bs) {
    const int* offs = p.routing; const int* cnt = p.routing + 8;
    int tid = threadIdx.x;
    int rt, ct, ks, Mloc, aRowBase; bool sh;
    const u16* Bsrc; const float* bias;
    if (j < 128) {
        sh = true; rt = j >> 3; int sub = j & 7; ct = sub >> 1; ks = sub & 1;
        Mloc = 128; aRowBase = 4096 + rt * 128;
        Bsrc = p.Wt2 + (size_t)8 * DD * FF; bias = p.bs2;
    } else {
        sh = false; int jr = j - 128; rt = jr >> 6; int rem = jr & 63;
        int e = rem >> 3; int sub = rem & 7; ct = sub >> 1; ks = sub & 1;
        int M = cnt[e]; if (rt * 128 >= M) return;
        Mloc = M - rt * 128; aRowBase = offs[e] + rt * 128;
        Bsrc = p.Wt2 + (size_t)e * DD * FF; bias = p.b2 + e * DD;
    }
    int n0 = ct * 128;
    int lane = tid & 63, w = tid >> 6, ln = lane & 15, quad = lane >> 4;
    int l8 = lane & 7, lh = lane >> 3;
    int gc = (l8 ^ lh) * 8;
    const u16* Asrc = p.hbuf + (size_t)aRowBase * FF;
    const u16* Ab = Asrc + (size_t)(w * 32 + lh) * FF + gc;
    const u16* Bb = Bsrc + (size_t)(n0 + w * 32 + lh) * FF + gc;
    float4v acc[4][4];
#pragma unroll
    for (int a = 0; a < 4; ++a)
#pragma unroll
        for (int b = 0; b < 4; ++b) acc[a][b] = (float4v){0.f, 0.f, 0.f, 0.f};
    for (int kt = 0; kt < 16; ++kt) {
        int k0 = ks * 1024 + kt * 64;
#pragma unroll
        for (int i = 0; i < 4; ++i) {
            gl_lds16(Ab + (size_t)(i * 8) * FF + k0, &As[(w * 4 + i) * 512]);
            gl_lds16(Bb + (size_t)(i * 8) * FF + k0, &Bs[(w * 4 + i) * 512]);
        }
        __syncthreads();
#pragma unroll
        for (int s = 0; s < 2; ++s) {
            short8 Af[4], Bf[4];
#pragma unroll
            for (int a = 0; a < 4; ++a) {
                int m = (w & 1) * 64 + a * 16 + ln;
                Af[a] = *(const short8*)&As[m * 64 + (((s * 4 + quad) ^ (ln & 7)) * 8)];
            }
#pragma unroll
            for (int b = 0; b < 4; ++b) {
                int m = (w >> 1) * 64 + b * 16 + ln;
                Bf[b] = *(const short8*)&Bs[m * 64 + (((s * 4 + quad) ^ (ln & 7)) * 8)];
            }
#pragma unroll
            for (int a = 0; a < 4; ++a)
#pragma unroll
                for (int b = 0; b < 4; ++b)
                    acc[a][b] = __builtin_amdgcn_mfma_f32_16x16x32_bf16(Af[a], Bf[b], acc[a][b], 0, 0, 0);
        }
        __syncthreads();
    }
    float bv[4];
#pragma unroll
    for (int b = 0; b < 4; ++b)
        bv[b] = (ks == 0) ? bias[n0 + (w >> 1) * 64 + b * 16 + ln] : 0.f;
    if (p.useYb) {
        // deterministic ownership: plain stores, zero atomics
#pragma unroll
        for (int a = 0; a < 4; ++a) {
#pragma unroll
            for (int i = 0; i < 4; ++i) {
                int lr = (w & 1) * 64 + a * 16 + quad * 4 + i;
                if (lr < Mloc) {
                    int row = aRowBase + lr;
                    float wr = sh ? 0.5f : p.wrow[row];
                    float* yp = p.ybuf + ((size_t)ks * 6144 + row) * DD;
#pragma unroll
                    for (int b = 0; b < 4; ++b) {
                        int n = n0 + (w >> 1) * 64 + b * 16 + ln;
                        yp[n] = wr * (acc[a][b][i] + bv[b]);
                    }
                }
            }
        }
    } else {
#pragma unroll
        for (int a = 0; a < 4; ++a) {
#pragma unroll
            for (int i = 0; i < 4; ++i) {
                int lr = (w & 1) * 64 + a * 16 + quad * 4 + i;
                if (lr < Mloc) {
                    int row = aRowBase + lr;
                    int t; float wr;
                    if (sh) { t = row - 4096; wr = 0.5f; }
                    else    { t = p.rtok[row]; wr = p.wrow[row]; }
                    float* op = p.out + (size_t)t * DD;
#pragma unroll
                    for (int b = 0; b < 4; ++b) {
                        int n = n0 + (w >> 1) * 64 + b * 16 + ln;
                        atomicAdd(op + n, wr * (acc[a][b][i] + bv[b]));
                    }
                }
            }
        }
    }
}

// ---------------- combine: out[t] = sum of 6 ybuf partials ----------------
__device__ void combine_job(int j, const Params& p) {
    int tid = threadIdx.x, wv = tid >> 6, lane = tid & 63;
    int t = j * 4 + wv;
    int r0 = p.metaR[2 * t], r1 = p.metaR[2 * t + 1];
    int d = lane * 8;
    float4v s0 = (float4v){0.f, 0.f, 0.f, 0.f};
    float4v s1 = (float4v){0.f, 0.f, 0.f, 0.f};
#pragma unroll
    for (int ks = 0; ks < 2; ++ks) {
        const float* a = p.ybuf + ((size_t)ks * 6144 + r0) * DD + d;
        const float* b = p.ybuf + ((size_t)ks * 6144 + r1) * DD + d;
        const float* c = p.ybuf + ((size_t)ks * 6144 + 4096 + t) * DD + d;
        s0 += *(const float4v*)a + *(const float4v*)b + *(const float4v*)c;
        s1 += *(const float4v*)(a + 4) + *(const float4v*)(b + 4) + *(const float4v*)(c + 4);
    }
    *(float4v*)(p.out + (size_t)t * DD + d) = s0;
    *(float4v*)(p.out + (size_t)t * DD + d + 4) = s1;
}

// ---------------- single cooperative mega-kernel (NO min-wave bound!) ----------------
__global__ __launch_bounds__(256) void mega_k(Params p) {
    __shared__ __align__(16) char smem[32768];
    u16* As = (u16*)smem;
    u16* Bs = (u16*)(smem + 16384);
    u16* Ls = (u16*)smem;
    cg::grid_group grid = cg::this_grid();
    int b = blockIdx.x, tid = threadIdx.x, G = gridDim.x;

    // P0: conv1 (+conv2 if separate Wt2) + gate (+ out-zero for atomic path)
    if (p.useYb) {
        for (int j = b; j < 5120; j += G) {
            if (j < 2304)      conv_unit(j, p.W1, p.Ws1, p.Wt1, DD, FF, 5, Ls);
            else if (j < 4608) conv_unit(j - 2304, p.W2, p.Ws2, p.Wt2, FF, DD, 3, Ls);
            else               gate_wave((j - 4608) * 4 + (tid >> 6), tid & 63, p);
        }
    } else {
        for (int j = b; j < 2944; j += G) {
            if (j < 2304)      conv_unit(j, p.W1, p.Ws1, p.Wt1, DD, FF, 5, Ls);
            else if (j < 2816) gate_wave((j - 2304) * 4 + (tid >> 6), tid & 63, p);
            else {
                float* op = p.out + (size_t)(j - 2816) * 8192;
#pragma unroll
                for (int it = 0; it < 8; ++it)
                    *(float4v*)(op + it * 1024 + tid * 4) = (float4v){0.f, 0.f, 0.f, 0.f};
            }
        }
    }
    grid.sync();
    // P1: rank
    if (b == 0) rank_block(p, smem);
    grid.sync();
    // P2: gemmA
    for (int j = b; j < 2304; j += G) gemmA_job(j, p, As, Bs);
    grid.sync();
    // P3: conv2 into Wt1 slab (small-ws path only; Wt1 dead after gemmA)
    if (!p.useYb) {
        for (int j = b; j < 2304; j += G) conv_unit(j, p.W2, p.Ws2, p.Wt2, FF, DD, 3, Ls);
    }
    grid.sync();
    // P4: gemmB
    for (int j = b; j < 1152; j += G) gemmB_job(j, p, As, Bs);
    // P5: combine (ybuf path)
    if (p.useYb) {
        grid.sync();
        for (int j = b; j < 512; j += G) combine_job(j, p);
    }
}

// ---------------- launcher ----------------
extern "C" void kernel_launch(void* const* d_in, const int* in_sizes, int n_in,
                              void* d_out, int out_size, void* d_ws, size_t ws_size,
                              hipStream_t stream) {
    char* ws = (char*)d_ws;
    Params p;
    p.x   = (const float*)d_in[0];
    p.Wg  = (const float*)d_in[1];
    p.bg  = (const float*)d_in[2];
    p.W1  = (const float*)d_in[3];
    p.b1  = (const float*)d_in[4];
    p.W2  = (const float*)d_in[5];
    p.b2  = (const float*)d_in[6];
    p.Ws1 = (const float*)d_in[7];
    p.bs1 = (const float*)d_in[8];
    p.Ws2 = (const float*)d_in[9];
    p.bs2 = (const float*)d_in[10];
    p.out = (float*)d_out;
    p.hbuf    = (u16*)(ws + WS_HB);
    p.xg      = (u16*)(ws + WS_XG);
    p.Wt1     = (u16*)(ws + WS_WT1);
    p.routing = (int*)(ws + WS_RTG);
    p.metaE   = (int*)(ws + WS_ME);
    p.metaW   = (float*)(ws + WS_MW);
    p.rtok    = (int*)(ws + WS_RT);
    p.wrow    = (float*)(ws + WS_WROW);
    p.metaR   = (int*)(ws + WS_MR);
    p.useYb   = (ws_size >= WS_BIG) ? 1 : 0;
    p.Wt2     = p.useYb ? (u16*)(ws + WS_WT2) : p.Wt1;
    p.ybuf    = (float*)(ws + WS_YB);

    int maxB = 0;
    hipOccupancyMaxActiveBlocksPerMultiprocessor(&maxB, mega_k, 256, 0);
    if (maxB < 1) maxB = 1;
    if (maxB > 4) maxB = 4;
    dim3 gridD(256 * maxB), blockD(256);
    void* kp[] = { (void*)&p };
    hipLaunchCooperativeKernel((void*)mega_k, gridD, blockD, kp, 0, stream);
}

// Round 8
// 315.020 us; speedup vs baseline: 1.3780x; 1.3780x over previous
//
#include <hip/hip_runtime.h>
#include <hip/hip_cooperative_groups.h>
#include <hip/hip_bf16.h>
#include <stdint.h>

namespace cg = cooperative_groups;

// Problem constants (S=1024, B=2 -> T=2048 tokens)
#define TT 2048
#define DD 512
#define FF 2048
#define EE 8

typedef unsigned short u16;
typedef __attribute__((ext_vector_type(8))) unsigned short ushort8v;
typedef __attribute__((ext_vector_type(8))) short short8;     // bf16x8 frag
typedef __attribute__((ext_vector_type(4))) float float4v;

__device__ __forceinline__ u16 f2bf(float f) {
    unsigned u = __float_as_uint(f);
    u += 0x7FFF + ((u >> 16) & 1);   // round-to-nearest-even
    return (u16)(u >> 16);
}

// async global->LDS, 16B/lane; LDS dest = wave-uniform base + lane*16.
__device__ __forceinline__ void gl_lds16(const u16* g, u16* l) {
    __builtin_amdgcn_global_load_lds(
        (const __attribute__((address_space(1))) unsigned int*)g,
        (__attribute__((address_space(3))) unsigned int*)l, 16, 0, 0);
}

// ---------------- workspace layout (bytes) ----------------
#define WS_HB   0ull                                // hbuf bf16 [6144][2048]
#define WS_XG   (WS_HB + 6144ull*2048*2)            // xg bf16 [2048][512]
#define WS_WT1  (WS_XG + 2048ull*512*2)             // W1t bf16 [9][F][D]
#define WS_RTG  (WS_WT1 + 9ull*2048*512*2)          // routing int[16] = offs[8],cnt[8]
#define WS_ME   (WS_RTG + 64)                       // int  [2048][2]
#define WS_MW   (WS_ME + 16384)                     // float[2048][2]
#define WS_RT   (WS_MW + 16384)                     // int  rtok[4096]
#define WS_WROW (WS_RT + 16384)                     // float wrow[4096]
#define WS_WT2  (WS_WROW + 16384)                   // W2t bf16 [9][D][F]
#define WS_NEED (WS_WT2 + 9ull*2048*512*2)          // ~65.1 MB (round-7 confirmed ws >= 90 MB)

// ---------------- conv unit: fp32 [R][C] 64x64 tile -> bf16 [C][R] ----------------
__device__ __forceinline__ void conv_unit(int j, const float* __restrict__ srcE,
                                          const float* __restrict__ srcS,
                                          u16* __restrict__ dst,
                                          int R, int C, int shC, u16* Ls) {
    int mid = j >> 8, t2 = j & 255;
    int tr = t2 >> shC, tc = t2 & ((1 << shC) - 1);
    int r0 = tr * 64, c0 = tc * 64;
    const float* src = (mid < 8) ? srcE + (size_t)mid * R * C : srcS;
    u16* dstm = dst + (size_t)mid * R * C;
    int t = threadIdx.x;
#pragma unroll
    for (int i = 0; i < 4; ++i) {
        int rr = (t >> 4) + i * 16;
        int cc = (t & 15) * 4;
        float4v v = *(const float4v*)(src + (size_t)(r0 + rr) * C + c0 + cc);
#pragma unroll
        for (int jx = 0; jx < 4; ++jx) Ls[(cc + jx) * 72 + rr] = f2bf(v[jx]);
    }
    __syncthreads();
#pragma unroll
    for (int jj = 0; jj < 2; ++jj) {
        int slot = t + jj * 256;
        int cc = slot >> 3, r8 = (slot & 7) * 8;
        ushort8v o = *(const ushort8v*)&Ls[cc * 72 + r8];
        *(ushort8v*)(dstm + (size_t)(c0 + cc) * R + r0 + r8) = o;
    }
    __syncthreads();   // WAR guard (job loop reuses Ls)
}

// ---------------- gate: one wave per token (fp32 logits = np ref) ----------------
__device__ __forceinline__ void gate_wave(int t, int lane,
                                          const float* __restrict__ x,
                                          const float* __restrict__ Wg,
                                          const float* __restrict__ bg,
                                          int* __restrict__ metaE,
                                          float* __restrict__ metaW,
                                          u16* __restrict__ xg) {
    const float* xp = x + (size_t)t * DD + lane * 8;
    float4v x0 = *(const float4v*)xp;
    float4v x1 = *(const float4v*)(xp + 4);
    float xf[8] = {x0[0], x0[1], x0[2], x0[3], x1[0], x1[1], x1[2], x1[3]};
    float acc[EE] = {0.f, 0.f, 0.f, 0.f, 0.f, 0.f, 0.f, 0.f};
#pragma unroll
    for (int g = 0; g < 8; ++g) {
        const float* wp = Wg + (size_t)(lane * 8 + g) * EE;
        float4v w0 = *(const float4v*)wp;
        float4v w1 = *(const float4v*)(wp + 4);
        acc[0] += xf[g] * w0[0]; acc[1] += xf[g] * w0[1];
        acc[2] += xf[g] * w0[2]; acc[3] += xf[g] * w0[3];
        acc[4] += xf[g] * w1[0]; acc[5] += xf[g] * w1[1];
        acc[6] += xf[g] * w1[2]; acc[7] += xf[g] * w1[3];
    }
#pragma unroll
    for (int off = 1; off < 64; off <<= 1) {
#pragma unroll
        for (int e = 0; e < EE; ++e) acc[e] += __shfl_xor(acc[e], off, 64);
    }
    ushort8v xv;
#pragma unroll
    for (int jx = 0; jx < 4; ++jx) xv[jx] = f2bf(x0[jx]);
#pragma unroll
    for (int jx = 0; jx < 4; ++jx) xv[4 + jx] = f2bf(x1[jx]);
    *(ushort8v*)(xg + (size_t)t * DD + lane * 8) = xv;
    if (lane == 0) {
#pragma unroll
        for (int e = 0; e < EE; ++e) acc[e] += bg[e];
        int e0 = 0; float l0 = acc[0];
#pragma unroll
        for (int e = 1; e < EE; ++e) if (acc[e] > l0) { l0 = acc[e]; e0 = e; }
        int e1 = -1; float l1 = -3.4e38f;
#pragma unroll
        for (int e = 0; e < EE; ++e)
            if (e != e0 && acc[e] > l1) { l1 = acc[e]; e1 = e; }
        float ex = __expf(l1 - l0);
        float w0 = 1.f / (1.f + ex);
        metaE[2 * t] = e0; metaE[2 * t + 1] = e1;
        metaW[2 * t] = w0; metaW[2 * t + 1] = 1.f - w0;
    }
}

// ---------------- prep: cooperative (conv1 + gate + zero-out; sync; rank) ----------
__global__ __launch_bounds__(256) void prep_k(
    const float* x, const float* Wg, const float* bg,
    const float* W1, const float* Ws1, float* out, u16* xg, u16* Wt1,
    int* routing, int* metaE, float* metaW, int* rtok, float* wrow) {
    __shared__ __align__(16) char smem[16384];
    u16* Ls = (u16*)smem;
    cg::grid_group grid = cg::this_grid();
    int b = blockIdx.x, tid = threadIdx.x, G = gridDim.x;
    // P0: conv1 (2304) + gate (512) + zero-out (128)
    for (int j = b; j < 2944; j += G) {
        if (j < 2304) conv_unit(j, W1, Ws1, Wt1, DD, FF, 5, Ls);
        else if (j < 2816) gate_wave((j - 2304) * 4 + (tid >> 6), tid & 63,
                                     x, Wg, bg, metaE, metaW, xg);
        else {
            float* op = out + (size_t)(j - 2816) * 8192;
#pragma unroll
            for (int it = 0; it < 8; ++it)
                *(float4v*)(op + it * 1024 + tid * 4) = (float4v){0.f, 0.f, 0.f, 0.f};
        }
    }
    grid.sync();
    // P1: rank (block 0, 256 threads, ballot-based, 0 atomics)
    if (b == 0) {
        u16* er      = (u16*)smem;            // 4096 x u16 (e | rk<<4)
        int* segCnt  = (int*)(smem + 8192);   // [64][8]
        int* segBase = (int*)(smem + 10240);  // [64][8]
        int* expTot  = (int*)(smem + 12288);  // [16]
        int wv = tid >> 6, lane = tid & 63;
        unsigned long long below = (lane == 0) ? 0ull : ((~0ull) >> (64 - lane));
        for (int s = wv * 16; s < wv * 16 + 16; ++s) {
            int entry = s * 64 + lane;
            int e = metaE[entry];
            int rk = 0;
#pragma unroll
            for (int ee = 0; ee < 8; ++ee) {
                unsigned long long m = __ballot(e == ee);
                if (e == ee) rk = __popcll(m & below);
                if (lane == ee) segCnt[s * 8 + ee] = __popcll(m);
            }
            er[entry] = (u16)(e | (rk << 4));
        }
        __syncthreads();
        if (tid < 8) {
            int s = 0;
            for (int g = 0; g < 64; ++g) { segBase[g * 8 + tid] = s; s += segCnt[g * 8 + tid]; }
            expTot[tid] = s;
        }
        __syncthreads();
        if (tid == 0) {
            int s = 0;
            for (int e = 0; e < 8; ++e) { int c = expTot[e]; expTot[8 + e] = s; s += c; }
        }
        __syncthreads();
        if (tid < 8) { routing[tid] = expTot[8 + tid]; routing[8 + tid] = expTot[tid]; }
        for (int i = 0; i < 16; ++i) {
            int entry = tid + i * 256;
            int v = er[entry];
            int e = v & 15, rk = v >> 4;
            int row = expTot[8 + e] + segBase[(entry >> 6) * 8 + e] + rk;
            rtok[row] = entry >> 1;
            wrow[row] = metaW[entry];
        }
    }
}

// ---------------- GEMM A (M=64,N=128,BK=64 two-plane) + conv2 blocks -------------
// jobs: [0,512) shared (rt5|ct4); [512,4608) routed (rt5|e3|ct4); [4608,6912) conv2.
__global__ __launch_bounds__(256) void gemmA_k(
    const u16* __restrict__ xg, const u16* __restrict__ Wt1,
    const float* __restrict__ b1, const float* __restrict__ bs1,
    const int* __restrict__ routing, const int* __restrict__ rtok,
    u16* __restrict__ hbuf,
    const float* __restrict__ W2, const float* __restrict__ Ws2,
    u16* __restrict__ Wt2, int doConv2) {
    __shared__ __align__(16) u16 As[2 * 64 * 32];    // 8 KB  (2 planes)
    __shared__ __align__(16) u16 Bs[2 * 128 * 32];   // 16 KB (2 planes)
    int j = blockIdx.x, tid = threadIdx.x;
    if (j >= 4608) {                      // conv2 lane
        if (doConv2) conv_unit(j - 4608, W2, Ws2, Wt2, FF, DD, 3, As);
        return;
    }
    const int* offs = routing; const int* cnt = routing + 8;
    int rt, ct, Mloc, hRowBase, rowBase; bool routed;
    const u16* Bsrc; const float* bias;
    if (j < 512) {
        rt = j >> 4; ct = j & 15; Mloc = 64; rowBase = rt * 64;
        Bsrc = Wt1 + (size_t)8 * FF * DD; bias = bs1;
        hRowBase = 4096 + rt * 64; routed = false;
    } else {
        int jr = j - 512; rt = jr >> 7; int rem = jr & 127;
        int e = rem >> 4; ct = rem & 15;
        int M = cnt[e]; if (rt * 64 >= M) return;
        Mloc = M - rt * 64; if (Mloc > 64) Mloc = 64;
        rowBase = offs[e] + rt * 64;
        Bsrc = Wt1 + (size_t)e * FF * DD; bias = b1 + e * FF;
        hRowBase = rowBase; routed = true;
    }
    int n0 = ct * 128;
    int lane = tid & 63, w = tid >> 6, ln = lane & 15, quad = lane >> 4;
    int rsub = lane >> 2;                       // 0..15 row within segment
    int chunk = ((lane & 3) ^ ((lane >> 3) & 3)) * 8;  // round-6 swizzle (0 conflicts)
    // A: wave w stages rows w*16..+16 (gathered); B: rows (2w)..(2w+1) segs
    const u16 *Ab[2], *Bb[2][2];
    {
        int r = w * 16 + rsub;
        int tok;
        if (routed) {
            int br = rowBase + r; if (br > 4095) br = 4095;   // finite, masked below
            tok = rtok[br];
        } else tok = rowBase + r;
#pragma unroll
        for (int q = 0; q < 2; ++q) Ab[q] = xg + (size_t)tok * DD + q * 32 + chunk;
#pragma unroll
        for (int i = 0; i < 2; ++i) {
            int nl = (2 * w + i) * 16 + rsub;
#pragma unroll
            for (int q = 0; q < 2; ++q)
                Bb[i][q] = Bsrc + (size_t)(n0 + nl) * DD + q * 32 + chunk;
        }
    }
    float4v acc[2][4];
#pragma unroll
    for (int a = 0; a < 2; ++a)
#pragma unroll
        for (int b = 0; b < 4; ++b) acc[a][b] = (float4v){0.f, 0.f, 0.f, 0.f};
    for (int kt = 0; kt < 8; ++kt) {
        int k0 = kt * 64;
#pragma unroll
        for (int q = 0; q < 2; ++q) {
            gl_lds16(Ab[q] + k0, &As[q * 2048 + w * 512]);
            gl_lds16(Bb[0][q] + k0, &Bs[q * 4096 + (2 * w) * 512]);
            gl_lds16(Bb[1][q] + k0, &Bs[q * 4096 + (2 * w + 1) * 512]);
        }
        __syncthreads();
        int slot = (quad ^ ((ln >> 1) & 3)) * 8;
#pragma unroll
        for (int s = 0; s < 2; ++s) {
            short8 Af[2], Bf[4];
#pragma unroll
            for (int a = 0; a < 2; ++a)
                Af[a] = *(const short8*)&As[s * 2048 + ((w & 1) * 32 + a * 16 + ln) * 32 + slot];
#pragma unroll
            for (int b = 0; b < 4; ++b)
                Bf[b] = *(const short8*)&Bs[s * 4096 + ((w >> 1) * 64 + b * 16 + ln) * 32 + slot];
#pragma unroll
            for (int a = 0; a < 2; ++a)
#pragma unroll
                for (int b = 0; b < 4; ++b)
                    acc[a][b] = __builtin_amdgcn_mfma_f32_16x16x32_bf16(Af[a], Bf[b], acc[a][b], 0, 0, 0);
        }
        __syncthreads();
    }
#pragma unroll
    for (int b = 0; b < 4; ++b) {
        int n = n0 + (w >> 1) * 64 + b * 16 + ln;
        float bv = bias[n];
#pragma unroll
        for (int a = 0; a < 2; ++a) {
#pragma unroll
            for (int i = 0; i < 4; ++i) {
                int lr = (w & 1) * 32 + a * 16 + quad * 4 + i;
                if (lr < Mloc) {
                    float v = acc[a][b][i] + bv;
                    v = v > 0.f ? v : 0.f;
                    hbuf[(size_t)(hRowBase + lr) * FF + n] = f2bf(v);
                }
            }
        }
    }
}

// ---------------- GEMM B (M=64,N=128,BK=64 two-plane, K-split x2, atomics) --------
// jobs: [0,256) shared (rt5|ct2|ks1); [256,2304) routed (rt5|e3|ct2|ks1).
__global__ __launch_bounds__(256) void gemmB_k(
    const u16* __restrict__ hbuf, const u16* __restrict__ Wt2,
    const float* __restrict__ b2, const float* __restrict__ bs2,
    const int* __restrict__ routing, const int* __restrict__ rtok,
    const float* __restrict__ wrow, float* __restrict__ out) {
    __shared__ __align__(16) u16 As[2 * 64 * 32];
    __shared__ __align__(16) u16 Bs[2 * 128 * 32];
    const int* offs = routing; const int* cnt = routing + 8;
    int j = blockIdx.x, tid = threadIdx.x;
    int rt, ct, ks, Mloc, aRowBase; bool sh;
    const u16* Bsrc; const float* bias;
    if (j < 256) {
        sh = true; rt = j >> 3; int sub = j & 7; ct = sub >> 1; ks = sub & 1;
        Mloc = 64; aRowBase = 4096 + rt * 64;
        Bsrc = Wt2 + (size_t)8 * DD * FF; bias = bs2;
    } else {
        sh = false; int jr = j - 256; rt = jr >> 6; int rem = jr & 63;
        int e = rem >> 3; int sub = rem & 7; ct = sub >> 1; ks = sub & 1;
        int M = cnt[e]; if (rt * 64 >= M) return;
        Mloc = M - rt * 64; if (Mloc > 64) Mloc = 64;
        aRowBase = offs[e] + rt * 64;
        Bsrc = Wt2 + (size_t)e * DD * FF; bias = b2 + e * DD;
    }
    int n0 = ct * 128;
    int lane = tid & 63, w = tid >> 6, ln = lane & 15, quad = lane >> 4;
    int rsub = lane >> 2;
    int chunk = ((lane & 3) ^ ((lane >> 3) & 3)) * 8;
    const u16 *Ab[2], *Bb[2][2];
    {
        int r = w * 16 + rsub;
#pragma unroll
        for (int q = 0; q < 2; ++q)
            Ab[q] = hbuf + (size_t)(aRowBase + r) * FF + ks * 1024 + q * 32 + chunk;
#pragma unroll
        for (int i = 0; i < 2; ++i) {
            int nl = (2 * w + i) * 16 + rsub;
#pragma unroll
            for (int q = 0; q < 2; ++q)
                Bb[i][q] = Bsrc + (size_t)(n0 + nl) * FF + ks * 1024 + q * 32 + chunk;
        }
    }
    float4v acc[2][4];
#pragma unroll
    for (int a = 0; a < 2; ++a)
#pragma unroll
        for (int b = 0; b < 4; ++b) acc[a][b] = (float4v){0.f, 0.f, 0.f, 0.f};
    for (int kt = 0; kt < 16; ++kt) {
        int k0 = kt * 64;
#pragma unroll
        for (int q = 0; q < 2; ++q) {
            gl_lds16(Ab[q] + k0, &As[q * 2048 + w * 512]);
            gl_lds16(Bb[0][q] + k0, &Bs[q * 4096 + (2 * w) * 512]);
            gl_lds16(Bb[1][q] + k0, &Bs[q * 4096 + (2 * w + 1) * 512]);
        }
        __syncthreads();
        int slot = (quad ^ ((ln >> 1) & 3)) * 8;
#pragma unroll
        for (int s = 0; s < 2; ++s) {
            short8 Af[2], Bf[4];
#pragma unroll
            for (int a = 0; a < 2; ++a)
                Af[a] = *(const short8*)&As[s * 2048 + ((w & 1) * 32 + a * 16 + ln) * 32 + slot];
#pragma unroll
            for (int b = 0; b < 4; ++b)
                Bf[b] = *(const short8*)&Bs[s * 4096 + ((w >> 1) * 64 + b * 16 + ln) * 32 + slot];
#pragma unroll
            for (int a = 0; a < 2; ++a)
#pragma unroll
                for (int b = 0; b < 4; ++b)
                    acc[a][b] = __builtin_amdgcn_mfma_f32_16x16x32_bf16(Af[a], Bf[b], acc[a][b], 0, 0, 0);
        }
        __syncthreads();
    }
    float bv[4];
#pragma unroll
    for (int b = 0; b < 4; ++b)
        bv[b] = (ks == 0) ? bias[n0 + (w >> 1) * 64 + b * 16 + ln] : 0.f;
#pragma unroll
    for (int a = 0; a < 2; ++a) {
#pragma unroll
        for (int i = 0; i < 4; ++i) {
            int lr = (w & 1) * 32 + a * 16 + quad * 4 + i;
            if (lr < Mloc) {
                int row = aRowBase + lr;
                int t; float wr;
                if (sh) { t = row - 4096; wr = 0.5f; }
                else    { t = rtok[row]; wr = wrow[row]; }
                float* op = out + (size_t)t * DD;
#pragma unroll
                for (int b = 0; b < 4; ++b) {
                    int n = n0 + (w >> 1) * 64 + b * 16 + ln;
                    atomicAdd(op + n, wr * (acc[a][b][i] + bv[b]));
                }
            }
        }
    }
}

// ---------------- conv2 standalone (small-ws fallback) ----------------
__global__ __launch_bounds__(256) void conv2_k(const float* __restrict__ W2,
                                               const float* __restrict__ Ws2,
                                               u16* __restrict__ Wt2) {
    __shared__ __align__(16) u16 Ls[64 * 72];
    conv_unit(blockIdx.x, W2, Ws2, Wt2, FF, DD, 3, Ls);
}

// ---------------- launcher ----------------
extern "C" void kernel_launch(void* const* d_in, const int* in_sizes, int n_in,
                              void* d_out, int out_size, void* d_ws, size_t ws_size,
                              hipStream_t stream) {
    const float* x   = (const float*)d_in[0];
    const float* Wg  = (const float*)d_in[1];
    const float* bg  = (const float*)d_in[2];
    const float* W1  = (const float*)d_in[3];
    const float* b1  = (const float*)d_in[4];
    const float* W2  = (const float*)d_in[5];
    const float* b2  = (const float*)d_in[6];
    const float* Ws1 = (const float*)d_in[7];
    const float* bs1 = (const float*)d_in[8];
    const float* Ws2 = (const float*)d_in[9];
    const float* bs2 = (const float*)d_in[10];
    float* out = (float*)d_out;

    char* ws = (char*)d_ws;
    u16*   hbuf    = (u16*)(ws + WS_HB);
    u16*   xg      = (u16*)(ws + WS_XG);
    u16*   Wt1     = (u16*)(ws + WS_WT1);
    int*   routing = (int*)(ws + WS_RTG);
    int*   metaE   = (int*)(ws + WS_ME);
    float* metaW   = (float*)(ws + WS_MW);
    int*   rtok    = (int*)(ws + WS_RT);
    float* wrow    = (float*)(ws + WS_WROW);
    bool   big     = ws_size >= WS_NEED;
    u16*   Wt2     = big ? (u16*)(ws + WS_WT2) : Wt1;

    // node 1: cooperative prep (conv1 + gate + out-zero; grid.sync; rank)
    int maxB = 0;
    hipOccupancyMaxActiveBlocksPerMultiprocessor(&maxB, prep_k, 256, 0);
    if (maxB < 1) maxB = 1;
    int gP = 256 * maxB; if (gP > 2944) gP = 2944;
    void* a1[] = { (void*)&x, (void*)&Wg, (void*)&bg, (void*)&W1, (void*)&Ws1,
                   (void*)&out, (void*)&xg, (void*)&Wt1, (void*)&routing,
                   (void*)&metaE, (void*)&metaW, (void*)&rtok, (void*)&wrow };
    hipLaunchCooperativeKernel((void*)prep_k, dim3(gP), dim3(256), a1, 0, stream);

    // node 2: gemmA (+ conv2 overlapped, big-ws path)
    int doConv2 = big ? 1 : 0;
    int gA = big ? 6912 : 4608;
    gemmA_k<<<gA, 256, 0, stream>>>(xg, Wt1, b1, bs1, routing, rtok, hbuf,
                                    W2, Ws2, Wt2, doConv2);
    if (!big) conv2_k<<<2304, 256, 0, stream>>>(W2, Ws2, Wt2);

    // node 3: gemmB
    gemmB_k<<<2304, 256, 0, stream>>>(hbuf, Wt2, b2, bs2, routing, rtok, wrow, out);
}

// Round 9
// 220.697 us; speedup vs baseline: 1.9669x; 1.4274x over previous
//
#include <hip/hip_runtime.h>
#include <hip/hip_bf16.h>
#include <stdint.h>

// Problem constants (S=1024, B=2 -> T=2048 tokens)
#define TT 2048
#define DD 512
#define FF 2048
#define EE 8

typedef unsigned short u16;
typedef __attribute__((ext_vector_type(8))) unsigned short ushort8v;
typedef __attribute__((ext_vector_type(8))) short short8;     // bf16x8 frag
typedef __attribute__((ext_vector_type(4))) float float4v;

__device__ __forceinline__ u16 f2bf(float f) {
    unsigned u = __float_as_uint(f);
    u += 0x7FFF + ((u >> 16) & 1);   // round-to-nearest-even
    return (u16)(u >> 16);
}

// async global->LDS, 16B/lane; LDS dest = wave-uniform base + lane*16.
__device__ __forceinline__ void gl_lds16(const u16* g, u16* l) {
    __builtin_amdgcn_global_load_lds(
        (const __attribute__((address_space(1))) unsigned int*)g,
        (__attribute__((address_space(3))) unsigned int*)l, 16, 0, 0);
}

// ---------------- workspace layout (bytes) ----------------
#define WS_HB   0ull                                // hbuf bf16 [6144][2048]
#define WS_XG   (WS_HB + 6144ull*2048*2)            // xg bf16 [2048][512]
#define WS_WT1  (WS_XG + 2048ull*512*2)             // W1t bf16 [9][F][D]
#define WS_RTG  (WS_WT1 + 9ull*2048*512*2)          // routing int[16] = offs[8],cnt[8]
#define WS_ME   (WS_RTG + 64)                       // int  [2048][2]
#define WS_MW   (WS_ME + 16384)                     // float[2048][2]
#define WS_RT   (WS_MW + 16384)                     // int  rtok[4096]
#define WS_WROW (WS_RT + 16384)                     // float wrow[4096]
#define WS_WT2  (WS_WROW + 16384)                   // W2t bf16 [9][D][F]
#define WS_NEED (WS_WT2 + 9ull*2048*512*2)          // ~65.1 MB (R7 proved ws >= 90 MB)

// ---------------- conv unit: fp32 [R][C] 64x64 tile -> bf16 [C][R] ----------------
__device__ __forceinline__ void conv_unit(int j, const float* __restrict__ srcE,
                                          const float* __restrict__ srcS,
                                          u16* __restrict__ dst,
                                          int R, int C, int shC, u16* Ls) {
    int mid = j >> 8, t2 = j & 255;
    int tr = t2 >> shC, tc = t2 & ((1 << shC) - 1);
    int r0 = tr * 64, c0 = tc * 64;
    const float* src = (mid < 8) ? srcE + (size_t)mid * R * C : srcS;
    u16* dstm = dst + (size_t)mid * R * C;
    int t = threadIdx.x;
#pragma unroll
    for (int i = 0; i < 4; ++i) {
        int rr = (t >> 4) + i * 16;
        int cc = (t & 15) * 4;
        float4v v = *(const float4v*)(src + (size_t)(r0 + rr) * C + c0 + cc);
#pragma unroll
        for (int jx = 0; jx < 4; ++jx) Ls[(cc + jx) * 72 + rr] = f2bf(v[jx]);
    }
    __syncthreads();
#pragma unroll
    for (int jj = 0; jj < 2; ++jj) {
        int slot = t + jj * 256;
        int cc = slot >> 3, r8 = (slot & 7) * 8;
        ushort8v o = *(const ushort8v*)&Ls[cc * 72 + r8];
        *(ushort8v*)(dstm + (size_t)(c0 + cc) * R + r0 + r8) = o;
    }
}

// ---------------- gate: one wave per token (fp32 logits = np ref) ----------------
__device__ __forceinline__ void gate_wave(int t, int lane,
                                          const float* __restrict__ x,
                                          const float* __restrict__ Wg,
                                          const float* __restrict__ bg,
                                          int* __restrict__ metaE,
                                          float* __restrict__ metaW,
                                          u16* __restrict__ xg) {
    const float* xp = x + (size_t)t * DD + lane * 8;
    float4v x0 = *(const float4v*)xp;
    float4v x1 = *(const float4v*)(xp + 4);
    float xf[8] = {x0[0], x0[1], x0[2], x0[3], x1[0], x1[1], x1[2], x1[3]};
    float acc[EE] = {0.f, 0.f, 0.f, 0.f, 0.f, 0.f, 0.f, 0.f};
#pragma unroll
    for (int g = 0; g < 8; ++g) {
        const float* wp = Wg + (size_t)(lane * 8 + g) * EE;
        float4v w0 = *(const float4v*)wp;
        float4v w1 = *(const float4v*)(wp + 4);
        acc[0] += xf[g] * w0[0]; acc[1] += xf[g] * w0[1];
        acc[2] += xf[g] * w0[2]; acc[3] += xf[g] * w0[3];
        acc[4] += xf[g] * w1[0]; acc[5] += xf[g] * w1[1];
        acc[6] += xf[g] * w1[2]; acc[7] += xf[g] * w1[3];
    }
#pragma unroll
    for (int off = 1; off < 64; off <<= 1) {
#pragma unroll
        for (int e = 0; e < EE; ++e) acc[e] += __shfl_xor(acc[e], off, 64);
    }
    ushort8v xv;
#pragma unroll
    for (int jx = 0; jx < 4; ++jx) xv[jx] = f2bf(x0[jx]);
#pragma unroll
    for (int jx = 0; jx < 4; ++jx) xv[4 + jx] = f2bf(x1[jx]);
    *(ushort8v*)(xg + (size_t)t * DD + lane * 8) = xv;
    if (lane == 0) {
#pragma unroll
        for (int e = 0; e < EE; ++e) acc[e] += bg[e];
        int e0 = 0; float l0 = acc[0];
#pragma unroll
        for (int e = 1; e < EE; ++e) if (acc[e] > l0) { l0 = acc[e]; e0 = e; }
        int e1 = -1; float l1 = -3.4e38f;
#pragma unroll
        for (int e = 0; e < EE; ++e)
            if (e != e0 && acc[e] > l1) { l1 = acc[e]; e1 = e; }
        float ex = __expf(l1 - l0);
        float w0 = 1.f / (1.f + ex);
        metaE[2 * t] = e0; metaE[2 * t + 1] = e1;
        metaW[2 * t] = w0; metaW[2 * t + 1] = 1.f - w0;
    }
}

// ---------------- fused phase-1 (regular launch; R6-proven structure) ----------------
// jobs: [0,nconv) conv (conv1, then conv2 when fused); [nconv,+512) gate; [+128) zero.
__global__ __launch_bounds__(256) void fused1_k(
    const float* __restrict__ x, const float* __restrict__ Wg,
    const float* __restrict__ bg,
    const float* __restrict__ W1, const float* __restrict__ Ws1,
    const float* __restrict__ W2, const float* __restrict__ Ws2,
    float* __restrict__ out, u16* __restrict__ xg,
    u16* __restrict__ Wt1, u16* __restrict__ Wt2,
    int* __restrict__ metaE, float* __restrict__ metaW, int nconv) {
    __shared__ __align__(16) u16 Ls[64 * 72];
    int b = blockIdx.x, tid = threadIdx.x;
    if (b < nconv) {
        if (b < 2304) conv_unit(b, W1, Ws1, Wt1, DD, FF, 5, Ls);
        else          conv_unit(b - 2304, W2, Ws2, Wt2, FF, DD, 3, Ls);
    } else if (b < nconv + 512) {
        int gb = b - nconv;
        gate_wave(gb * 4 + (tid >> 6), tid & 63, x, Wg, bg, metaE, metaW, xg);
    } else {
        int zb = b - nconv - 512;          // 128 blocks x 8192 floats = 2048*512
        float* op = out + (size_t)zb * 8192;
#pragma unroll
        for (int it = 0; it < 8; ++it)
            *(float4v*)(op + it * 1024 + tid * 4) = (float4v){0.f, 0.f, 0.f, 0.f};
    }
}

// ---------------- conv2 standalone (small-ws fallback) ----------------
__global__ __launch_bounds__(256) void conv2_k(const float* __restrict__ W2,
                                               const float* __restrict__ Ws2,
                                               u16* __restrict__ Wt2) {
    __shared__ __align__(16) u16 Ls[64 * 72];
    conv_unit(blockIdx.x, W2, Ws2, Wt2, FF, DD, 3, Ls);
}

// ---------------- rank: 1 block x 256, ballot-based, 0 atomics ----------------
__global__ __launch_bounds__(256) void rank_k(const int* __restrict__ metaE,
                                              const float* __restrict__ metaW,
                                              int* __restrict__ routing,
                                              int* __restrict__ rtok,
                                              float* __restrict__ wrow) {
    __shared__ __align__(16) char smem[16384];
    u16* er      = (u16*)smem;            // 4096 x u16 (e | rk<<4)
    int* segCnt  = (int*)(smem + 8192);   // [64][8]
    int* segBase = (int*)(smem + 10240);  // [64][8]
    int* expTot  = (int*)(smem + 12288);  // [16]
    int tid = threadIdx.x, wv = tid >> 6, lane = tid & 63;
    unsigned long long below = (lane == 0) ? 0ull : ((~0ull) >> (64 - lane));
    for (int s = wv * 16; s < wv * 16 + 16; ++s) {
        int entry = s * 64 + lane;
        int e = metaE[entry];
        int rk = 0;
#pragma unroll
        for (int ee = 0; ee < 8; ++ee) {
            unsigned long long m = __ballot(e == ee);
            if (e == ee) rk = __popcll(m & below);
            if (lane == ee) segCnt[s * 8 + ee] = __popcll(m);
        }
        er[entry] = (u16)(e | (rk << 4));
    }
    __syncthreads();
    if (tid < 8) {
        int s = 0;
        for (int g = 0; g < 64; ++g) { segBase[g * 8 + tid] = s; s += segCnt[g * 8 + tid]; }
        expTot[tid] = s;
    }
    __syncthreads();
    if (tid == 0) {
        int s = 0;
        for (int e = 0; e < 8; ++e) { int c = expTot[e]; expTot[8 + e] = s; s += c; }
    }
    __syncthreads();
    if (tid < 8) { routing[tid] = expTot[8 + tid]; routing[8 + tid] = expTot[tid]; }
    for (int i = 0; i < 16; ++i) {
        int entry = tid + i * 256;
        int v = er[entry];
        int e = v & 15, rk = v >> 4;
        int row = expTot[8 + e] + segBase[(entry >> 6) * 8 + e] + rk;
        rtok[row] = entry >> 1;
        wrow[row] = metaW[entry];
    }
}

// ---------------- GEMM A (M=64,N=128,BK=64 two-plane, XCD-affine) ----------------
// jobs: [0,512) shared (rt5|ct4); [512,4608) routed: j-512 = (rt*16+ct)*8 + e
// so blockIdx%8 == e -> expert weight slab stays in one XCD's L2.
__global__ __launch_bounds__(256) void gemmA_k(
    const u16* __restrict__ xg, const u16* __restrict__ Wt1,
    const float* __restrict__ b1, const float* __restrict__ bs1,
    const int* __restrict__ routing, const int* __restrict__ rtok,
    u16* __restrict__ hbuf) {
    __shared__ __align__(16) u16 As[2 * 64 * 32];    // 8 KB  (2 k-planes)
    __shared__ __align__(16) u16 Bs[2 * 128 * 32];   // 16 KB (2 k-planes)
    const int* offs = routing; const int* cnt = routing + 8;
    int j = blockIdx.x, tid = threadIdx.x;
    int rt, ct, Mloc, hRowBase, rowBase; bool routed;
    const u16* Bsrc; const float* bias;
    if (j < 512) {
        rt = j >> 4; ct = j & 15; Mloc = 64; rowBase = rt * 64;
        Bsrc = Wt1 + (size_t)8 * FF * DD; bias = bs1;
        hRowBase = 4096 + rt * 64; routed = false;
    } else {
        int jr = j - 512; int e = jr & 7; int rc = jr >> 3;
        rt = rc >> 4; ct = rc & 15;
        int M = cnt[e]; if (rt * 64 >= M) return;
        Mloc = M - rt * 64; if (Mloc > 64) Mloc = 64;
        rowBase = offs[e] + rt * 64;
        Bsrc = Wt1 + (size_t)e * FF * DD; bias = b1 + e * FF;
        hRowBase = rowBase; routed = true;
    }
    int n0 = ct * 128;
    int lane = tid & 63, w = tid >> 6, ln = lane & 15, quad = lane >> 4;
    int rsub = lane >> 2;                              // row within 16-row segment
    int chunk = ((lane & 3) ^ ((lane >> 3) & 3)) * 8;  // 0-conflict swizzle (R6-measured)
    const u16 *Ab[2], *Bb[2][2];
    {
        int r = w * 16 + rsub;
        int tok;
        if (routed) {
            int br = rowBase + r; if (br > 4095) br = 4095;   // finite, masked below
            tok = rtok[br];
        } else tok = rowBase + r;
#pragma unroll
        for (int q = 0; q < 2; ++q) Ab[q] = xg + (size_t)tok * DD + q * 32 + chunk;
#pragma unroll
        for (int i = 0; i < 2; ++i) {
            int nl = (2 * w + i) * 16 + rsub;
#pragma unroll
            for (int q = 0; q < 2; ++q)
                Bb[i][q] = Bsrc + (size_t)(n0 + nl) * DD + q * 32 + chunk;
        }
    }
    float4v acc[2][4];
#pragma unroll
    for (int a = 0; a < 2; ++a)
#pragma unroll
        for (int b = 0; b < 4; ++b) acc[a][b] = (float4v){0.f, 0.f, 0.f, 0.f};
    for (int kt = 0; kt < 8; ++kt) {
        int k0 = kt * 64;
#pragma unroll
        for (int q = 0; q < 2; ++q) {
            gl_lds16(Ab[q] + k0, &As[q * 2048 + w * 512]);
            gl_lds16(Bb[0][q] + k0, &Bs[q * 4096 + (2 * w) * 512]);
            gl_lds16(Bb[1][q] + k0, &Bs[q * 4096 + (2 * w + 1) * 512]);
        }
        __syncthreads();
        int slot = (quad ^ ((ln >> 1) & 3)) * 8;
#pragma unroll
        for (int s = 0; s < 2; ++s) {
            short8 Af[2], Bf[4];
#pragma unroll
            for (int a = 0; a < 2; ++a)
                Af[a] = *(const short8*)&As[s * 2048 + ((w & 1) * 32 + a * 16 + ln) * 32 + slot];
#pragma unroll
            for (int b = 0; b < 4; ++b)
                Bf[b] = *(const short8*)&Bs[s * 4096 + ((w >> 1) * 64 + b * 16 + ln) * 32 + slot];
#pragma unroll
            for (int a = 0; a < 2; ++a)
#pragma unroll
                for (int b = 0; b < 4; ++b)
                    acc[a][b] = __builtin_amdgcn_mfma_f32_16x16x32_bf16(Af[a], Bf[b], acc[a][b], 0, 0, 0);
        }
        __syncthreads();
    }
#pragma unroll
    for (int b = 0; b < 4; ++b) {
        int n = n0 + (w >> 1) * 64 + b * 16 + ln;
        float bv = bias[n];
#pragma unroll
        for (int a = 0; a < 2; ++a) {
#pragma unroll
            for (int i = 0; i < 4; ++i) {
                int lr = (w & 1) * 32 + a * 16 + quad * 4 + i;
                if (lr < Mloc) {
                    float v = acc[a][b][i] + bv;
                    v = v > 0.f ? v : 0.f;
                    hbuf[(size_t)(hRowBase + lr) * FF + n] = f2bf(v);
                }
            }
        }
    }
}

// ---------------- GEMM B (M=64,N=128,BK=64, K-split x2, atomics, XCD-affine) -------
// jobs: [0,256) shared (rt5|ct2|ks1); [256,2304): j-256 = (rt*8 + ct*2 + ks)*8 + e.
__global__ __launch_bounds__(256) void gemmB_k(
    const u16* __restrict__ hbuf, const u16* __restrict__ Wt2,
    const float* __restrict__ b2, const float* __restrict__ bs2,
    const int* __restrict__ routing, const int* __restrict__ rtok,
    const float* __restrict__ wrow, float* __restrict__ out) {
    __shared__ __align__(16) u16 As[2 * 64 * 32];
    __shared__ __align__(16) u16 Bs[2 * 128 * 32];
    const int* offs = routing; const int* cnt = routing + 8;
    int j = blockIdx.x, tid = threadIdx.x;
    int rt, ct, ks, Mloc, aRowBase; bool sh;
    const u16* Bsrc; const float* bias;
    if (j < 256) {
        sh = true; rt = j >> 3; int sub = j & 7; ct = sub >> 1; ks = sub & 1;
        Mloc = 64; aRowBase = 4096 + rt * 64;
        Bsrc = Wt2 + (size_t)8 * DD * FF; bias = bs2;
    } else {
        sh = false; int jr = j - 256; int e = jr & 7; int rc = jr >> 3;
        rt = rc >> 3; ct = (rc >> 1) & 3; ks = rc & 1;
        int M = cnt[e]; if (rt * 64 >= M) return;
        Mloc = M - rt * 64; if (Mloc > 64) Mloc = 64;
        aRowBase = offs[e] + rt * 64;
        Bsrc = Wt2 + (size_t)e * DD * FF; bias = b2 + e * DD;
    }
    int n0 = ct * 128;
    int lane = tid & 63, w = tid >> 6, ln = lane & 15, quad = lane >> 4;
    int rsub = lane >> 2;
    int chunk = ((lane & 3) ^ ((lane >> 3) & 3)) * 8;
    const u16 *Ab[2], *Bb[2][2];
    {
        int r = w * 16 + rsub;
#pragma unroll
        for (int q = 0; q < 2; ++q)
            Ab[q] = hbuf + (size_t)(aRowBase + r) * FF + ks * 1024 + q * 32 + chunk;
#pragma unroll
        for (int i = 0; i < 2; ++i) {
            int nl = (2 * w + i) * 16 + rsub;
#pragma unroll
            for (int q = 0; q < 2; ++q)
                Bb[i][q] = Bsrc + (size_t)(n0 + nl) * FF + ks * 1024 + q * 32 + chunk;
        }
    }
    float4v acc[2][4];
#pragma unroll
    for (int a = 0; a < 2; ++a)
#pragma unroll
        for (int b = 0; b < 4; ++b) acc[a][b] = (float4v){0.f, 0.f, 0.f, 0.f};
    for (int kt = 0; kt < 16; ++kt) {
        int k0 = kt * 64;
#pragma unroll
        for (int q = 0; q < 2; ++q) {
            gl_lds16(Ab[q] + k0, &As[q * 2048 + w * 512]);
            gl_lds16(Bb[0][q] + k0, &Bs[q * 4096 + (2 * w) * 512]);
            gl_lds16(Bb[1][q] + k0, &Bs[q * 4096 + (2 * w + 1) * 512]);
        }
        __syncthreads();
        int slot = (quad ^ ((ln >> 1) & 3)) * 8;
#pragma unroll
        for (int s = 0; s < 2; ++s) {
            short8 Af[2], Bf[4];
#pragma unroll
            for (int a = 0; a < 2; ++a)
                Af[a] = *(const short8*)&As[s * 2048 + ((w & 1) * 32 + a * 16 + ln) * 32 + slot];
#pragma unroll
            for (int b = 0; b < 4; ++b)
                Bf[b] = *(const short8*)&Bs[s * 4096 + ((w >> 1) * 64 + b * 16 + ln) * 32 + slot];
#pragma unroll
            for (int a = 0; a < 2; ++a)
#pragma unroll
                for (int b = 0; b < 4; ++b)
                    acc[a][b] = __builtin_amdgcn_mfma_f32_16x16x32_bf16(Af[a], Bf[b], acc[a][b], 0, 0, 0);
        }
        __syncthreads();
    }
    float bv[4];
#pragma unroll
    for (int b = 0; b < 4; ++b)
        bv[b] = (ks == 0) ? bias[n0 + (w >> 1) * 64 + b * 16 + ln] : 0.f;
#pragma unroll
    for (int a = 0; a < 2; ++a) {
#pragma unroll
        for (int i = 0; i < 4; ++i) {
            int lr = (w & 1) * 32 + a * 16 + quad * 4 + i;
            if (lr < Mloc) {
                int row = aRowBase + lr;
                int t; float wr;
                if (sh) { t = row - 4096; wr = 0.5f; }
                else    { t = rtok[row]; wr = wrow[row]; }
                float* op = out + (size_t)t * DD;
#pragma unroll
                for (int b = 0; b < 4; ++b) {
                    int n = n0 + (w >> 1) * 64 + b * 16 + ln;
                    atomicAdd(op + n, wr * (acc[a][b][i] + bv[b]));
                }
            }
        }
    }
}

// ---------------- launcher (ALL regular launches — coop is 3-5x slower here) -------
extern "C" void kernel_launch(void* const* d_in, const int* in_sizes, int n_in,
                              void* d_out, int out_size, void* d_ws, size_t ws_size,
                              hipStream_t stream) {
    const float* x   = (const float*)d_in[0];
    const float* Wg  = (const float*)d_in[1];
    const float* bg  = (const float*)d_in[2];
    const float* W1  = (const float*)d_in[3];
    const float* b1  = (const float*)d_in[4];
    const float* W2  = (const float*)d_in[5];
    const float* b2  = (const float*)d_in[6];
    const float* Ws1 = (const float*)d_in[7];
    const float* bs1 = (const float*)d_in[8];
    const float* Ws2 = (const float*)d_in[9];
    const float* bs2 = (const float*)d_in[10];
    float* out = (float*)d_out;

    char* ws = (char*)d_ws;
    u16*   hbuf    = (u16*)(ws + WS_HB);
    u16*   xg      = (u16*)(ws + WS_XG);
    u16*   Wt1     = (u16*)(ws + WS_WT1);
    int*   routing = (int*)(ws + WS_RTG);
    int*   metaE   = (int*)(ws + WS_ME);
    float* metaW   = (float*)(ws + WS_MW);
    int*   rtok    = (int*)(ws + WS_RT);
    float* wrow    = (float*)(ws + WS_WROW);
    bool   big     = ws_size >= WS_NEED;
    u16*   Wt2     = big ? (u16*)(ws + WS_WT2) : Wt1;
    int    nconv   = big ? 4608 : 2304;   // conv2 fused only with its own buffer

    fused1_k<<<nconv + 640, 256, 0, stream>>>(x, Wg, bg, W1, Ws1, W2, Ws2,
                                              out, xg, Wt1, Wt2, metaE, metaW, nconv);
    rank_k<<<1, 256, 0, stream>>>(metaE, metaW, routing, rtok, wrow);
    gemmA_k<<<4608, 256, 0, stream>>>(xg, Wt1, b1, bs1, routing, rtok, hbuf);
    if (!big) conv2_k<<<2304, 256, 0, stream>>>(W2, Ws2, Wt2);
    gemmB_k<<<2304, 256, 0, stream>>>(hbuf, Wt2, b2, bs2, routing, rtok, wrow, out);
}